// Round 9
// baseline (367.541 us; speedup 1.0000x reference)
//
#include <hip/hip_runtime.h>
#include <hip/hip_bf16.h>
#include <hip/hip_fp16.h>

#define NN 100000
#define NG 256
#define NE 800000

constexpr int F0 = 114;   // x features
constexpr int F1 = 230;   // layer1 output features
constexpr int F2 = 115;   // layer2 output features
constexpr int MPAD = 100096;  // 782 * 128

typedef _Float16 __attribute__((ext_vector_type(8))) f16x8;   // MFMA operand
typedef __attribute__((ext_vector_type(4))) float f32x4;      // MFMA acc
typedef __attribute__((ext_vector_type(8))) unsigned short u16x8;

__device__ __forceinline__ unsigned short f2h_bits(float x) {
  _Float16 h = (_Float16)x;
  return __builtin_bit_cast(unsigned short, h);
}
__device__ __forceinline__ float h_bits2f(unsigned short u) {
  return (float)__builtin_bit_cast(_Float16, u);
}

// ---------------- degree / CSR build ----------------

__global__ void k_count(const int* __restrict__ dst, int* __restrict__ cnt) {
  int e = blockIdx.x * blockDim.x + threadIdx.x;
  if (e < NE) atomicAdd(&cnt[dst[e]], 1);
}

__global__ void k_dinv(const int* __restrict__ cnt, float* __restrict__ dinv) {
  int i = blockIdx.x * blockDim.x + threadIdx.x;
  if (i < NN) dinv[i] = rsqrtf((float)cnt[i] + 1.0f);
}

constexpr int SCAN_T = 256;
constexpr int SCAN_E = 1024;
constexpr int NB = (NN + SCAN_E - 1) / SCAN_E;  // 98

__global__ void k_scan1(const int* __restrict__ cnt, int* __restrict__ off,
                        int* __restrict__ bsum) {
  __shared__ int s[SCAN_T];
  int b = blockIdx.x, t = threadIdx.x;
  int base = b * SCAN_E + t * 4;
  int v0 = 0, v1 = 0, v2 = 0, v3 = 0;
  if (base + 0 < NN) v0 = cnt[base + 0];
  if (base + 1 < NN) v1 = cnt[base + 1];
  if (base + 2 < NN) v2 = cnt[base + 2];
  if (base + 3 < NN) v3 = cnt[base + 3];
  int sum = v0 + v1 + v2 + v3;
  s[t] = sum;
  __syncthreads();
  for (int ofs = 1; ofs < SCAN_T; ofs <<= 1) {
    int x = (t >= ofs) ? s[t - ofs] : 0;
    __syncthreads();
    s[t] += x;
    __syncthreads();
  }
  int excl = s[t] - sum;
  if (base + 0 < NN) off[base + 0] = excl;
  if (base + 1 < NN) off[base + 1] = excl + v0;
  if (base + 2 < NN) off[base + 2] = excl + v0 + v1;
  if (base + 3 < NN) off[base + 3] = excl + v0 + v1 + v2;
  if (t == SCAN_T - 1) bsum[b] = s[t];
}

__global__ void k_scan2(int* bsum) {
  if (threadIdx.x == 0) {
    int run = 0;
    for (int i = 0; i < NB; ++i) { int v = bsum[i]; bsum[i] = run; run += v; }
  }
}

__global__ void k_scan3(int* __restrict__ off, const int* __restrict__ bsum,
                        int* __restrict__ cur) {
  int i = blockIdx.x * blockDim.x + threadIdx.x;
  if (i < NN) {
    int v = off[i] + bsum[i / SCAN_E];
    off[i] = v;
    cur[i] = v;
  }
  if (i == NN) off[NN] = NE;
}

__global__ void k_place(const int* __restrict__ src, const int* __restrict__ dst,
                        int* __restrict__ cur, int* __restrict__ srcs) {
  int e = blockIdx.x * blockDim.x + threadIdx.x;
  if (e >= NE) return;
  int p = atomicAdd(&cur[dst[e]], 1);
  srcs[p] = src[e];
}

// ---------------- fp16 tables ----------------

// xd[n,f] = fp16(x[n,f] * dinv[n]), padded to 128 cols
__global__ void k_prepx(const float* __restrict__ x, const float* __restrict__ dinv,
                        unsigned short* __restrict__ xd) {
  int n = blockIdx.x, f = threadIdx.x;  // 128 threads
  float v = (f < F0) ? x[(size_t)n * F0 + f] * dinv[n] : 0.0f;
  xd[(size_t)n * 128 + f] = f2h_bits(v);
}

// ---------------- wave-per-node gather: 16 edge slots/iter, 4 loads in flight
// acc[n] = tab[n] + sum_j tab[srcs[j]]   (self appended as edge j1)
// POOL=false: out fp16 = acc * dinv[n]  (layer-1 aggX)
// POOL=true:  fused relu(acc*dinv + b2) -> block max -> atomicMax pooled

template <bool POOL>
__global__ __launch_bounds__(256) void k_gatherw(
    const unsigned short* __restrict__ tab, const float* __restrict__ dinv,
    const int* __restrict__ off, const int* __restrict__ srcs,
    const float* __restrict__ b2, const int* __restrict__ batch,
    unsigned short* __restrict__ outh, float* __restrict__ pooled) {
  __shared__ float smax[4][128];
  __shared__ int sg[4];
  int w = threadIdx.x >> 6, lane = threadIdx.x & 63;
  int n = blockIdx.x * 4 + w;
  int grp = lane >> 4, sub = lane & 15;
  int fb = sub * 8;

  float acc[8] = {0.f, 0.f, 0.f, 0.f, 0.f, 0.f, 0.f, 0.f};
  int j0 = off[n], j1 = off[n + 1];  // slots j0..j1, self at j1
  for (int base = j0; base <= j1; base += 16) {
    int row[4];
    u16x8 v[4];
    bool has[4];
#pragma unroll
    for (int c = 0; c < 4; ++c) {
      int je = base + c * 4 + grp;
      row[c] = (je < j1) ? srcs[je] : ((je == j1) ? n : -1);
      has[c] = row[c] >= 0;
    }
    // issue all loads before consuming any (4 KB/wave in flight)
#pragma unroll
    for (int c = 0; c < 4; ++c)
      if (has[c]) v[c] = *(const u16x8*)&tab[(size_t)row[c] * 128 + fb];
#pragma unroll
    for (int c = 0; c < 4; ++c)
      if (has[c]) {
#pragma unroll
        for (int u = 0; u < 8; ++u) acc[u] += h_bits2f(v[c][u]);
      }
  }
#pragma unroll
  for (int u = 0; u < 8; ++u) {
    acc[u] += __shfl_xor(acc[u], 16);
    acc[u] += __shfl_xor(acc[u], 32);
  }
  float dn = dinv[n];

  if constexpr (!POOL) {
    if (grp == 0) {
      u16x8 o;
#pragma unroll
      for (int u = 0; u < 8; ++u) o[u] = f2h_bits(acc[u] * dn);
      *(u16x8*)&outh[(size_t)n * 128 + fb] = o;
    }
  } else {
    if (grp == 0) {
#pragma unroll
      for (int u = 0; u < 8; ++u) {
        int f = fb + u;
        float bb = (f < F2) ? b2[f] : 0.0f;
        smax[w][f] = fmaxf(acc[u] * dn + bb, 0.0f);
      }
      if (sub == 0) sg[w] = batch[n];
    }
    __syncthreads();
    int t = threadIdx.x;
    if (t < 128) {
      int g0 = sg[0];
      bool same = (sg[1] == g0) & (sg[2] == g0) & (sg[3] == g0);
      if (same) {
        float m = fmaxf(fmaxf(smax[0][t], smax[1][t]),
                        fmaxf(smax[2][t], smax[3][t]));
        if (t < F2 && m > 0.0f)
          atomicMax((int*)&pooled[g0 * F2 + t], __float_as_int(m));
      } else {
        for (int ww = 0; ww < 4; ++ww) {
          float m = smax[ww][t];
          if (t < F2 && m > 0.0f)
            atomicMax((int*)&pooled[sg[ww] * F2 + t], __float_as_int(m));
        }
      }
    }
  }
}

// ---------------- weight split+transpose prep: Bt[n][k], fp16 hi/lo ----------------

__global__ void k_prepB(const float* __restrict__ W, unsigned short* __restrict__ Bh,
                        unsigned short* __restrict__ Bl, int K, int N, int KP) {
  int n = blockIdx.x, k = threadIdx.x;  // blockDim.x == KP
  float v = (k < K && n < N) ? W[(size_t)k * N + n] : 0.0f;
  unsigned short h = f2h_bits(v);
  unsigned short l = f2h_bits(v - h_bits2f(h));
  Bh[(size_t)n * KP + k] = h;
  Bl[(size_t)n * KP + k] = l;
}

// ---------------- fp16x2 MFMA GEMM, LDS-free k-loop: C = A @ (Bh+Bl)^T -----
// A fp16 single (exact as stored); weights fp16 hi/lo (~22-bit).
// A-frags and B-frags load straight from global (B is L2-resident, A streamed);
// zero barriers in the k-loop. LDS only for the coalesced fp16 epilogue.
// L1: +bias, relu, out stride 256 at col n0. !L1: *dscale[m], out stride 128.

template <int KP, bool L1>
__global__ __launch_bounds__(256) void k_mgemm(
    const unsigned short* __restrict__ A,
    const unsigned short* __restrict__ Bh, const unsigned short* __restrict__ Bl,
    const float* __restrict__ bias, const float* __restrict__ dscale,
    int Nvalid, unsigned short* __restrict__ C) {
  constexpr int SW = 136;  // epilogue LDS stride: 272B rows, 2-way bank alias (free)
  __shared__ unsigned short sw[128 * SW];  // 34.8 KB -> 4 blocks/CU

  int t = threadIdx.x;
  int m0 = blockIdx.y * 128, n0 = blockIdx.x * 128;
  int lane = t & 63, w = t >> 6;
  int wr = (w >> 1) * 64, wc = (w & 1) * 64;
  int r = lane & 15, kb = (lane >> 4) * 8;

  f32x4 acc[4][4];
#pragma unroll
  for (int i = 0; i < 4; ++i)
#pragma unroll
    for (int j = 0; j < 4; ++j) acc[i][j] = (f32x4){0.f, 0.f, 0.f, 0.f};

  const unsigned short* Ab  = A  + (size_t)(m0 + wr + r) * KP + kb;
  const unsigned short* Bhb = Bh + (size_t)(n0 + wc + r) * KP + kb;
  const unsigned short* Blb = Bl + (size_t)(n0 + wc + r) * KP + kb;

#pragma unroll
  for (int ks = 0; ks < KP / 32; ++ks) {
    int col = ks * 32;
    f16x8 a[4], bh4[4], bl4[4];
#pragma unroll
    for (int i = 0; i < 4; ++i) {
      a[i]   = *(const f16x8*)&Ab[(size_t)i * 16 * KP + col];
      bh4[i] = *(const f16x8*)&Bhb[(size_t)i * 16 * KP + col];
      bl4[i] = *(const f16x8*)&Blb[(size_t)i * 16 * KP + col];
    }
    // lo pass first (small terms), then hi
#pragma unroll
    for (int i = 0; i < 4; ++i)
#pragma unroll
      for (int j = 0; j < 4; ++j)
        acc[i][j] = __builtin_amdgcn_mfma_f32_16x16x32_f16(a[i], bl4[j], acc[i][j], 0, 0, 0);
#pragma unroll
    for (int i = 0; i < 4; ++i)
#pragma unroll
      for (int j = 0; j < 4; ++j)
        acc[i][j] = __builtin_amdgcn_mfma_f32_16x16x32_f16(a[i], bh4[j], acc[i][j], 0, 0, 0);
  }

  // epilogue: stage fp16 tile in LDS, write coalesced.
  // C/D layout: col = lane&15, row = (lane>>4)*4 + q  [m89/m91]
  int rq = (lane >> 4) * 4;
#pragma unroll
  for (int i = 0; i < 4; ++i) {
#pragma unroll
    for (int j = 0; j < 4; ++j) {
      int nl = wc + j * 16 + r;
#pragma unroll
      for (int q = 0; q < 4; ++q) {
        int ml = wr + i * 16 + rq + q;
        float v = acc[i][j][q];
        if constexpr (L1) {
          int n = n0 + nl;
          v = (n < Nvalid) ? fmaxf(v + bias[n], 0.0f) : 0.0f;
        } else {
          v *= dscale[m0 + ml];
        }
        sw[ml * SW + nl] = f2h_bits(v);
      }
    }
  }
  __syncthreads();
  int row = t >> 1, half = t & 1;
  const unsigned short* s = &sw[row * SW + half * 64];
  size_t dst = L1 ? ((size_t)(m0 + row) * 256 + n0 + half * 64)
                  : ((size_t)(m0 + row) * 128 + half * 64);
#pragma unroll
  for (int v = 0; v < 8; ++v)
    *(u16x8*)&C[dst + v * 8] = *(const u16x8*)&s[v * 8];
}

// ---------------- tiny MLP head: 115 -> 64 -> 32 -> 1 ----------------

__global__ void k_mlp(const float* __restrict__ pooled,
                      const float* __restrict__ Wg, const float* __restrict__ bg,
                      const float* __restrict__ Wf, const float* __restrict__ bf,
                      const float* __restrict__ Wo, const float* __restrict__ bo,
                      float* __restrict__ out) {
  __shared__ float sp[F2];
  __shared__ float sg[64];
  __shared__ float sf[32];
  int g = blockIdx.x, t = threadIdx.x;
  for (int f = t; f < F2; f += 64) sp[f] = pooled[g * F2 + f];
  __syncthreads();
  float a = bg[t];
  for (int k = 0; k < F2; ++k) a += sp[k] * Wg[k * 64 + t];
  sg[t] = fmaxf(a, 0.0f);
  __syncthreads();
  if (t < 32) {
    float c = bf[t];
    for (int k = 0; k < 64; ++k) c += sg[k] * Wf[k * 32 + t];
    sf[t] = fmaxf(c, 0.0f);
  }
  __syncthreads();
  if (t == 0) {
    float c = bo[0];
    for (int k = 0; k < 32; ++k) c += sf[k] * Wo[k];
    out[g] = c;
  }
}

// ---------------- launch ----------------

extern "C" void kernel_launch(void* const* d_in, const int* in_sizes, int n_in,
                              void* d_out, int out_size, void* d_ws, size_t ws_size,
                              hipStream_t stream) {
  const float* x  = (const float*)d_in[0];
  const int* ei   = (const int*)d_in[1];
  const int* batch = (const int*)d_in[2];
  const float* W1 = (const float*)d_in[3];
  const float* b1 = (const float*)d_in[4];
  const float* W2 = (const float*)d_in[5];
  const float* b2 = (const float*)d_in[6];
  const float* Wg = (const float*)d_in[7];
  const float* bg = (const float*)d_in[8];
  const float* Wf = (const float*)d_in[9];
  const float* bf = (const float*)d_in[10];
  const float* Wo = (const float*)d_in[11];
  const float* bo = (const float*)d_in[12];
  const int* src = ei;
  const int* dst = ei + NE;

  char* p = (char*)d_ws;
  auto alloc4 = [&](size_t units) { void* r = p; p += units * 4; return r; };
  float* dinv  = (float*)alloc4(100224);
  int* cnt     = (int*)alloc4(100224);
  int* off     = (int*)alloc4(100352);
  int* cur     = (int*)alloc4(100224);
  int* bsum    = (int*)alloc4(128);
  int* srcs    = (int*)alloc4(NE);
  unsigned short* xd   = (unsigned short*)alloc4((size_t)NN * 128 / 2);    // 25.6MB
  unsigned short* aggX = (unsigned short*)alloc4((size_t)MPAD * 128 / 2);  // 25.6MB
  unsigned short* td   = (unsigned short*)alloc4((size_t)MPAD * 128 / 2);  // 25.6MB
  unsigned short* h1   = (unsigned short*)alloc4((size_t)MPAD * 256 / 2);  // 51.2MB
  unsigned short* Bt1h = (unsigned short*)alloc4(256 * 128 / 2);
  unsigned short* Bt1l = (unsigned short*)alloc4(256 * 128 / 2);
  unsigned short* Bt2h = (unsigned short*)alloc4(128 * 256 / 2);
  unsigned short* Bt2l = (unsigned short*)alloc4(128 * 256 / 2);
  float* pooled = (float*)alloc4((size_t)NG * F2);

  hipMemsetAsync(cnt, 0, 100224 * sizeof(int), stream);
  hipMemsetAsync(pooled, 0, (size_t)NG * F2 * sizeof(float), stream);

  // CSR build (shared by both conv layers)
  k_count<<<(NE + 255) / 256, 256, 0, stream>>>(dst, cnt);
  k_dinv<<<(NN + 255) / 256, 256, 0, stream>>>(cnt, dinv);
  k_scan1<<<NB, SCAN_T, 0, stream>>>(cnt, off, bsum);
  k_scan2<<<1, 64, 0, stream>>>(bsum);
  k_scan3<<<(NN + 256) / 256, 256, 0, stream>>>(off, bsum, cur);
  k_place<<<(NE + 255) / 256, 256, 0, stream>>>(src, dst, cur, srcs);

  // weight prep (fp16 hi/lo, transposed, zero-padded)
  k_prepB<<<256, 128, 0, stream>>>(W1, Bt1h, Bt1l, F0, F1, 128);
  k_prepB<<<128, 256, 0, stream>>>(W2, Bt2h, Bt2l, F1, F2, 256);

  // layer 1: fp16 table, wave-per-node gather -> aggX fp16, MFMA GEMM -> h1 fp16
  k_prepx<<<NN, 128, 0, stream>>>(x, dinv, xd);
  k_gatherw<false><<<NN / 4, 256, 0, stream>>>(xd, dinv, off, srcs,
                                               nullptr, nullptr, aggX, nullptr);
  k_mgemm<128, true><<<dim3(2, MPAD / 128), 256, 0, stream>>>(
      aggX, Bt1h, Bt1l, b1, nullptr, F1, h1);

  // layer 2: MFMA GEMM -> td (fp16, dinv folded), then fused gather+pool
  k_mgemm<256, false><<<dim3(1, MPAD / 128), 256, 0, stream>>>(
      h1, Bt2h, Bt2l, nullptr, dinv, F2, td);
  k_gatherw<true><<<NN / 4, 256, 0, stream>>>(td, dinv, off, srcs,
                                              b2, batch, nullptr, pooled);

  // head MLP
  k_mlp<<<NG, 64, 0, stream>>>(pooled, Wg, bg, Wf, bf, Wo, bo, (float*)d_out);
}

// Round 10
// 307.889 us; speedup vs baseline: 1.1937x; 1.1937x over previous
//
#include <hip/hip_runtime.h>
#include <hip/hip_bf16.h>
#include <hip/hip_fp16.h>

#define NN 100000
#define NG 256
#define NE 800000

constexpr int F0 = 114;   // x features
constexpr int F1 = 230;   // layer1 output features
constexpr int F2 = 115;   // layer2 output features
constexpr int MPAD = 100096;  // 1564 * 64

typedef _Float16 __attribute__((ext_vector_type(8))) f16x8;   // MFMA operand
typedef __attribute__((ext_vector_type(4))) float f32x4;      // MFMA acc
typedef __attribute__((ext_vector_type(8))) unsigned short u16x8;

__device__ __forceinline__ unsigned short f2h_bits(float x) {
  _Float16 h = (_Float16)x;
  return __builtin_bit_cast(unsigned short, h);
}
__device__ __forceinline__ float h_bits2f(unsigned short u) {
  return (float)__builtin_bit_cast(_Float16, u);
}

// ---------------- degree / CSR build ----------------

__global__ void k_count(const int* __restrict__ dst, int* __restrict__ cnt) {
  int e = blockIdx.x * blockDim.x + threadIdx.x;
  if (e < NE) atomicAdd(&cnt[dst[e]], 1);
}

__global__ void k_dinv(const int* __restrict__ cnt, float* __restrict__ dinv) {
  int i = blockIdx.x * blockDim.x + threadIdx.x;
  if (i < NN) dinv[i] = rsqrtf((float)cnt[i] + 1.0f);
}

constexpr int SCAN_T = 256;
constexpr int SCAN_E = 1024;
constexpr int NB = (NN + SCAN_E - 1) / SCAN_E;  // 98

__global__ void k_scan1(const int* __restrict__ cnt, int* __restrict__ off,
                        int* __restrict__ bsum) {
  __shared__ int s[SCAN_T];
  int b = blockIdx.x, t = threadIdx.x;
  int base = b * SCAN_E + t * 4;
  int v0 = 0, v1 = 0, v2 = 0, v3 = 0;
  if (base + 0 < NN) v0 = cnt[base + 0];
  if (base + 1 < NN) v1 = cnt[base + 1];
  if (base + 2 < NN) v2 = cnt[base + 2];
  if (base + 3 < NN) v3 = cnt[base + 3];
  int sum = v0 + v1 + v2 + v3;
  s[t] = sum;
  __syncthreads();
  for (int ofs = 1; ofs < SCAN_T; ofs <<= 1) {
    int x = (t >= ofs) ? s[t - ofs] : 0;
    __syncthreads();
    s[t] += x;
    __syncthreads();
  }
  int excl = s[t] - sum;
  if (base + 0 < NN) off[base + 0] = excl;
  if (base + 1 < NN) off[base + 1] = excl + v0;
  if (base + 2 < NN) off[base + 2] = excl + v0 + v1;
  if (base + 3 < NN) off[base + 3] = excl + v0 + v1 + v2;
  if (t == SCAN_T - 1) bsum[b] = s[t];
}

__global__ void k_scan2(int* bsum) {
  if (threadIdx.x == 0) {
    int run = 0;
    for (int i = 0; i < NB; ++i) { int v = bsum[i]; bsum[i] = run; run += v; }
  }
}

__global__ void k_scan3(int* __restrict__ off, const int* __restrict__ bsum,
                        int* __restrict__ cur) {
  int i = blockIdx.x * blockDim.x + threadIdx.x;
  if (i < NN) {
    int v = off[i] + bsum[i / SCAN_E];
    off[i] = v;
    cur[i] = v;
  }
  if (i == NN) off[NN] = NE;
}

__global__ void k_place(const int* __restrict__ src, const int* __restrict__ dst,
                        int* __restrict__ cur, int* __restrict__ srcs) {
  int e = blockIdx.x * blockDim.x + threadIdx.x;
  if (e >= NE) return;
  int p = atomicAdd(&cur[dst[e]], 1);
  srcs[p] = src[e];
}

// ---------------- fp16 tables ----------------

// xd[n,f] = fp16(x[n,f] * dinv[n]), padded to 128 cols
__global__ void k_prepx(const float* __restrict__ x, const float* __restrict__ dinv,
                        unsigned short* __restrict__ xd) {
  int n = blockIdx.x, f = threadIdx.x;  // 128 threads
  float v = (f < F0) ? x[(size_t)n * F0 + f] * dinv[n] : 0.0f;
  xd[(size_t)n * 128 + f] = f2h_bits(v);
}

// ---------------- wave-per-node gather: 16 edge slots/iter, 4 loads in flight
// acc[n] = tab[n] + sum_j tab[srcs[j]]   (self appended as edge j1)
// POOL=false: out fp16 = acc * dinv[n]  (layer-1 aggX)
// POOL=true:  fused relu(acc*dinv + b2) -> block max -> atomicMax pooled

template <bool POOL>
__global__ __launch_bounds__(256) void k_gatherw(
    const unsigned short* __restrict__ tab, const float* __restrict__ dinv,
    const int* __restrict__ off, const int* __restrict__ srcs,
    const float* __restrict__ b2, const int* __restrict__ batch,
    unsigned short* __restrict__ outh, float* __restrict__ pooled) {
  __shared__ float smax[4][128];
  __shared__ int sg[4];
  int w = threadIdx.x >> 6, lane = threadIdx.x & 63;
  int n = blockIdx.x * 4 + w;
  int grp = lane >> 4, sub = lane & 15;
  int fb = sub * 8;

  float acc[8] = {0.f, 0.f, 0.f, 0.f, 0.f, 0.f, 0.f, 0.f};
  int j0 = off[n], j1 = off[n + 1];  // slots j0..j1, self at j1
  for (int base = j0; base <= j1; base += 16) {
    int row[4];
    u16x8 v[4];
    bool has[4];
#pragma unroll
    for (int c = 0; c < 4; ++c) {
      int je = base + c * 4 + grp;
      row[c] = (je < j1) ? srcs[je] : ((je == j1) ? n : -1);
      has[c] = row[c] >= 0;
    }
    // issue all loads before consuming any (4 KB/wave in flight)
#pragma unroll
    for (int c = 0; c < 4; ++c)
      if (has[c]) v[c] = *(const u16x8*)&tab[(size_t)row[c] * 128 + fb];
#pragma unroll
    for (int c = 0; c < 4; ++c)
      if (has[c]) {
#pragma unroll
        for (int u = 0; u < 8; ++u) acc[u] += h_bits2f(v[c][u]);
      }
  }
#pragma unroll
  for (int u = 0; u < 8; ++u) {
    acc[u] += __shfl_xor(acc[u], 16);
    acc[u] += __shfl_xor(acc[u], 32);
  }
  float dn = dinv[n];

  if constexpr (!POOL) {
    if (grp == 0) {
      u16x8 o;
#pragma unroll
      for (int u = 0; u < 8; ++u) o[u] = f2h_bits(acc[u] * dn);
      *(u16x8*)&outh[(size_t)n * 128 + fb] = o;
    }
  } else {
    if (grp == 0) {
#pragma unroll
      for (int u = 0; u < 8; ++u) {
        int f = fb + u;
        float bb = (f < F2) ? b2[f] : 0.0f;
        smax[w][f] = fmaxf(acc[u] * dn + bb, 0.0f);
      }
      if (sub == 0) sg[w] = batch[n];
    }
    __syncthreads();
    int t = threadIdx.x;
    if (t < 128) {
      int g0 = sg[0];
      bool same = (sg[1] == g0) & (sg[2] == g0) & (sg[3] == g0);
      if (same) {
        float m = fmaxf(fmaxf(smax[0][t], smax[1][t]),
                        fmaxf(smax[2][t], smax[3][t]));
        if (t < F2 && m > 0.0f)
          atomicMax((int*)&pooled[g0 * F2 + t], __float_as_int(m));
      } else {
        for (int ww = 0; ww < 4; ++ww) {
          float m = smax[ww][t];
          if (t < F2 && m > 0.0f)
            atomicMax((int*)&pooled[sg[ww] * F2 + t], __float_as_int(m));
        }
      }
    }
  }
}

// ---------------- weight split+transpose prep: Bt[n][k], fp16 hi/lo ----------------

__global__ void k_prepB(const float* __restrict__ W, unsigned short* __restrict__ Bh,
                        unsigned short* __restrict__ Bl, int K, int N, int KP) {
  int n = blockIdx.x, k = threadIdx.x;  // blockDim.x == KP
  float v = (k < K && n < N) ? W[(size_t)k * N + n] : 0.0f;
  unsigned short h = f2h_bits(v);
  unsigned short l = f2h_bits(v - h_bits2f(h));
  Bh[(size_t)n * KP + k] = h;
  Bl[(size_t)n * KP + k] = l;
}

// ---------------- fused double GEMM: td = (relu(aggX@W1t^T+b1) @ W2t^T)*dinv
// 64-row blocks; h1 tile lives ONLY in LDS (no HBM round-trip).
// A fp16 single; weights fp16 hi/lo (~22-bit). BK=64 LDS staging chunks.
// LDS: h1s 33.8KB + As 9.2KB + Bs 36.9KB = 79.9KB -> 2 blocks/CU.

__global__ __launch_bounds__(256) void k_fused(
    const unsigned short* __restrict__ A,                                   // [MPAD][128]
    const unsigned short* __restrict__ B1h, const unsigned short* __restrict__ B1l,  // [256][128]
    const unsigned short* __restrict__ B2h, const unsigned short* __restrict__ B2l,  // [128][256]
    const float* __restrict__ b1, const float* __restrict__ dscale,
    unsigned short* __restrict__ td) {                                      // [MPAD][128]
  constexpr int LDH = 264;  // h1s ushort stride (528B rows)
  constexpr int LD = 72;    // staging ushort stride (144B rows)
  __shared__ unsigned short h1s[64 * LDH];
  __shared__ unsigned short As[64 * LD];
  __shared__ unsigned short Bs[2][128 * LD];

  int t = threadIdx.x;
  int m0 = blockIdx.x * 64;
  int lane = t & 63, w = t >> 6;
  int r = lane & 15, kb = (lane >> 4) * 8;
  int rq = (lane >> 4) * 4;
  int wc = w * 32;  // this wave's 32-col slice

  // staging index precompute
  int arow = t >> 2, aq = t & 3;     // As: 64 rows x 4 x 16
  int brow = t >> 1, bs = t & 1;     // Bs: 128 rows x 2 x 32

  // ---------- stage 1: h1s = fp16(relu(aggX @ W1t^T + b1)) ----------
  for (int h = 0; h < 2; ++h) {
    f32x4 acc[4][2];
#pragma unroll
    for (int i = 0; i < 4; ++i)
#pragma unroll
      for (int j = 0; j < 2; ++j) acc[i][j] = (f32x4){0.f, 0.f, 0.f, 0.f};

    for (int kc = 0; kc < 2; ++kc) {
      __syncthreads();  // protect As/Bs from previous consumers
      {
        size_t ga = (size_t)(m0 + arow) * 128 + kc * 64 + aq * 16;
        *(u16x8*)&As[arow * LD + aq * 16]     = *(const u16x8*)&A[ga];
        *(u16x8*)&As[arow * LD + aq * 16 + 8] = *(const u16x8*)&A[ga + 8];
        size_t gb = (size_t)(h * 128 + brow) * 128 + kc * 64 + bs * 32;
        int lo = brow * LD + bs * 32;
#pragma unroll
        for (int v = 0; v < 4; ++v) {
          *(u16x8*)&Bs[0][lo + v * 8] = *(const u16x8*)&B1h[gb + v * 8];
          *(u16x8*)&Bs[1][lo + v * 8] = *(const u16x8*)&B1l[gb + v * 8];
        }
      }
      __syncthreads();
#pragma unroll
      for (int ks = 0; ks < 2; ++ks) {
        int col = ks * 32 + kb;
        f16x8 a[4], bh[2], bl[2];
#pragma unroll
        for (int i = 0; i < 4; ++i) a[i] = *(const f16x8*)&As[(i * 16 + r) * LD + col];
#pragma unroll
        for (int j = 0; j < 2; ++j) {
          bh[j] = *(const f16x8*)&Bs[0][(wc + j * 16 + r) * LD + col];
          bl[j] = *(const f16x8*)&Bs[1][(wc + j * 16 + r) * LD + col];
        }
#pragma unroll
        for (int i = 0; i < 4; ++i)
#pragma unroll
          for (int j = 0; j < 2; ++j)
            acc[i][j] = __builtin_amdgcn_mfma_f32_16x16x32_f16(a[i], bl[j], acc[i][j], 0, 0, 0);
#pragma unroll
        for (int i = 0; i < 4; ++i)
#pragma unroll
          for (int j = 0; j < 2; ++j)
            acc[i][j] = __builtin_amdgcn_mfma_f32_16x16x32_f16(a[i], bh[j], acc[i][j], 0, 0, 0);
      }
    }
    // bias+relu -> h1s (cols disjoint per wave; no race)
    // C/D layout: col = lane&15, row = (lane>>4)*4 + q  [m89/m91]
#pragma unroll
    for (int i = 0; i < 4; ++i)
#pragma unroll
      for (int j = 0; j < 2; ++j) {
        int nl = wc + j * 16 + r;
        int n = h * 128 + nl;
        float bb = (n < F1) ? b1[n] : 0.0f;
#pragma unroll
        for (int q = 0; q < 4; ++q) {
          int ml = i * 16 + rq + q;
          float v = (n < F1) ? fmaxf(acc[i][j][q] + bb, 0.0f) : 0.0f;
          h1s[ml * LDH + n] = f2h_bits(v);
        }
      }
  }

  // ---------- stage 2: t2 = (h1s @ W2t^T) * dscale[m] ----------
  f32x4 acc2[4][2];
#pragma unroll
  for (int i = 0; i < 4; ++i)
#pragma unroll
    for (int j = 0; j < 2; ++j) acc2[i][j] = (f32x4){0.f, 0.f, 0.f, 0.f};

  for (int kc = 0; kc < 4; ++kc) {
    __syncthreads();  // first iter also fences h1s writes
    {
      size_t gb = (size_t)brow * 256 + kc * 64 + bs * 32;
      int lo = brow * LD + bs * 32;
#pragma unroll
      for (int v = 0; v < 4; ++v) {
        *(u16x8*)&Bs[0][lo + v * 8] = *(const u16x8*)&B2h[gb + v * 8];
        *(u16x8*)&Bs[1][lo + v * 8] = *(const u16x8*)&B2l[gb + v * 8];
      }
    }
    __syncthreads();
#pragma unroll
    for (int ks = 0; ks < 2; ++ks) {
      int colA = kc * 64 + ks * 32 + kb;
      int colB = ks * 32 + kb;
      f16x8 a[4], bh[2], bl[2];
#pragma unroll
      for (int i = 0; i < 4; ++i) a[i] = *(const f16x8*)&h1s[(i * 16 + r) * LDH + colA];
#pragma unroll
      for (int j = 0; j < 2; ++j) {
        bh[j] = *(const f16x8*)&Bs[0][(wc + j * 16 + r) * LD + colB];
        bl[j] = *(const f16x8*)&Bs[1][(wc + j * 16 + r) * LD + colB];
      }
#pragma unroll
      for (int i = 0; i < 4; ++i)
#pragma unroll
        for (int j = 0; j < 2; ++j)
          acc2[i][j] = __builtin_amdgcn_mfma_f32_16x16x32_f16(a[i], bl[j], acc2[i][j], 0, 0, 0);
#pragma unroll
      for (int i = 0; i < 4; ++i)
#pragma unroll
        for (int j = 0; j < 2; ++j)
          acc2[i][j] = __builtin_amdgcn_mfma_f32_16x16x32_f16(a[i], bh[j], acc2[i][j], 0, 0, 0);
    }
  }

  // epilogue: scale, stage fp16 tile (reuse h1s), coalesced store
  __syncthreads();  // all h1s reads done
  constexpr int SW = 136;
  unsigned short* sw = h1s;
#pragma unroll
  for (int i = 0; i < 4; ++i)
#pragma unroll
    for (int j = 0; j < 2; ++j) {
      int nl = wc + j * 16 + r;
#pragma unroll
      for (int q = 0; q < 4; ++q) {
        int ml = i * 16 + rq + q;
        float v = acc2[i][j][q] * dscale[m0 + ml];
        sw[ml * SW + nl] = f2h_bits(v);
      }
    }
  __syncthreads();
  {
    int row = t >> 2, sgm = t & 3;
    const unsigned short* s = &sw[row * SW + sgm * 32];
    size_t dst = (size_t)(m0 + row) * 128 + sgm * 32;
#pragma unroll
    for (int v = 0; v < 4; ++v)
      *(u16x8*)&td[dst + v * 8] = *(const u16x8*)&s[v * 8];
  }
}

// ---------------- tiny MLP head: 115 -> 64 -> 32 -> 1 ----------------

__global__ void k_mlp(const float* __restrict__ pooled,
                      const float* __restrict__ Wg, const float* __restrict__ bg,
                      const float* __restrict__ Wf, const float* __restrict__ bf,
                      const float* __restrict__ Wo, const float* __restrict__ bo,
                      float* __restrict__ out) {
  __shared__ float sp[F2];
  __shared__ float sg[64];
  __shared__ float sf[32];
  int g = blockIdx.x, t = threadIdx.x;
  for (int f = t; f < F2; f += 64) sp[f] = pooled[g * F2 + f];
  __syncthreads();
  float a = bg[t];
  for (int k = 0; k < F2; ++k) a += sp[k] * Wg[k * 64 + t];
  sg[t] = fmaxf(a, 0.0f);
  __syncthreads();
  if (t < 32) {
    float c = bf[t];
    for (int k = 0; k < 64; ++k) c += sg[k] * Wf[k * 32 + t];
    sf[t] = fmaxf(c, 0.0f);
  }
  __syncthreads();
  if (t == 0) {
    float c = bo[0];
    for (int k = 0; k < 32; ++k) c += sf[k] * Wo[k];
    out[g] = c;
  }
}

// ---------------- launch ----------------

extern "C" void kernel_launch(void* const* d_in, const int* in_sizes, int n_in,
                              void* d_out, int out_size, void* d_ws, size_t ws_size,
                              hipStream_t stream) {
  const float* x  = (const float*)d_in[0];
  const int* ei   = (const int*)d_in[1];
  const int* batch = (const int*)d_in[2];
  const float* W1 = (const float*)d_in[3];
  const float* b1 = (const float*)d_in[4];
  const float* W2 = (const float*)d_in[5];
  const float* b2 = (const float*)d_in[6];
  const float* Wg = (const float*)d_in[7];
  const float* bg = (const float*)d_in[8];
  const float* Wf = (const float*)d_in[9];
  const float* bf = (const float*)d_in[10];
  const float* Wo = (const float*)d_in[11];
  const float* bo = (const float*)d_in[12];
  const int* src = ei;
  const int* dst = ei + NE;

  char* p = (char*)d_ws;
  auto alloc4 = [&](size_t units) { void* r = p; p += units * 4; return r; };
  float* dinv  = (float*)alloc4(100224);
  int* cnt     = (int*)alloc4(100224);
  int* off     = (int*)alloc4(100352);
  int* cur     = (int*)alloc4(100224);
  int* bsum    = (int*)alloc4(128);
  int* srcs    = (int*)alloc4(NE);
  unsigned short* xd   = (unsigned short*)alloc4((size_t)NN * 128 / 2);    // 25.6MB
  unsigned short* aggX = (unsigned short*)alloc4((size_t)MPAD * 128 / 2);  // 25.6MB
  unsigned short* td   = (unsigned short*)alloc4((size_t)MPAD * 128 / 2);  // 25.6MB
  unsigned short* Bt1h = (unsigned short*)alloc4(256 * 128 / 2);
  unsigned short* Bt1l = (unsigned short*)alloc4(256 * 128 / 2);
  unsigned short* Bt2h = (unsigned short*)alloc4(128 * 256 / 2);
  unsigned short* Bt2l = (unsigned short*)alloc4(128 * 256 / 2);
  float* pooled = (float*)alloc4((size_t)NG * F2);

  hipMemsetAsync(cnt, 0, 100224 * sizeof(int), stream);
  hipMemsetAsync(pooled, 0, (size_t)NG * F2 * sizeof(float), stream);

  // CSR build (shared by both conv layers)
  k_count<<<(NE + 255) / 256, 256, 0, stream>>>(dst, cnt);
  k_dinv<<<(NN + 255) / 256, 256, 0, stream>>>(cnt, dinv);
  k_scan1<<<NB, SCAN_T, 0, stream>>>(cnt, off, bsum);
  k_scan2<<<1, 64, 0, stream>>>(bsum);
  k_scan3<<<(NN + 256) / 256, 256, 0, stream>>>(off, bsum, cur);
  k_place<<<(NE + 255) / 256, 256, 0, stream>>>(src, dst, cur, srcs);

  // weight prep (fp16 hi/lo, transposed, zero-padded)
  k_prepB<<<256, 128, 0, stream>>>(W1, Bt1h, Bt1l, F0, F1, 128);
  k_prepB<<<128, 256, 0, stream>>>(W2, Bt2h, Bt2l, F1, F2, 256);

  // layer 1 input: fp16 table + wave-per-node gather -> aggX fp16
  k_prepx<<<NN, 128, 0, stream>>>(x, dinv, xd);
  k_gatherw<false><<<NN / 4, 256, 0, stream>>>(xd, dinv, off, srcs,
                                               nullptr, nullptr, aggX, nullptr);

  // fused conv1-GEMM + conv2-GEMM (h1 never leaves LDS) -> td fp16
  k_fused<<<MPAD / 64, 256, 0, stream>>>(aggX, Bt1h, Bt1l, Bt2h, Bt2l,
                                         b1, dinv, td);

  // layer 2 aggregation fused with relu(+b2) + per-graph max pool
  k_gatherw<true><<<NN / 4, 256, 0, stream>>>(td, dinv, off, srcs,
                                              b2, batch, nullptr, pooled);

  // head MLP
  k_mlp<<<NG, 64, 0, stream>>>(pooled, Wg, bg, Wf, bf, Wo, bo, (float*)d_out);
}